// Round 3
// baseline (251.288 us; speedup 1.0000x reference)
//
#include <hip/hip_runtime.h>

#define CCH 16
#define DD 64
#define HH 96
#define WW 96
#define HW (HH*WW)
#define DHW (DD*HH*WW)   // 589824
#define CH4 (DHW/4)      // 147456
#define NTH 768          // 16 lh x 48 lc, 2 w-sites per thread
#define DCH 16           // depth outputs per block
#define NBY (DD/DCH)     // 4 depth chunks
#define KTR 1.08f        // 27 * k_harris (S unscaled by 1/27; ranking-invariant)
#define INV27C (1.f/19683.f)

typedef float v2f __attribute__((ext_vector_type(2)));

// DPP row16 shifts: thread layout is lh-fast (lh = tid & 15), so a DPP row of
// 16 lanes == one h-column; bound_ctrl=true zero-fills at row ends (filled
// sites only feed masked-out outputs). Harris is invariant to an up/down swap.
__device__ __forceinline__ float dpp_up(float v) {
    return __int_as_float(__builtin_amdgcn_update_dpp(
        0, __float_as_int(v), 0x111 /*row_shr:1*/, 0xF, 0xF, true));
}
__device__ __forceinline__ float dpp_dn(float v) {
    return __int_as_float(__builtin_amdgcn_update_dpp(
        0, __float_as_int(v), 0x101 /*row_shl:1*/, 0xF, 0xF, true));
}

// R14: R12's proven skeleton (FULL unroll, load-at-top, no extra window stage
// -- R13's partial unroll + 3-deep prefetch spilled to scratch: WRITE_SIZE
// 3 KB -> 89 MB) with a slimmed body:
//  - branchless per-lane loads: row/edge-clamped offsets precomputed once,
//    3 always-valid dwordx2 loads + 3 v_pk_mul zero-masks; depth-OOB via one
//    UNIFORM branch (no exec-mask dances per slice).
//  - h-convs in paired-add form so GCNDPPCombine folds mov_dpp into
//    v_add_f32_dpp / v_sub_f32_dpp.
//  - packed w-convs (v_pk_sub), packed gradient masks (6 pk vs 12 scalar),
//    packed halo products ({gl,gr}^2), packed FIELD (Rv = Ph + {s,s}).
//  - emit-row mask applied ONCE at the end (all intermediate garbage is
//    finite), not per slice.
__global__ __launch_bounds__(NTH, 6)
void harris_sum_kernel(const float* __restrict__ x, float* __restrict__ pp) {
    __shared__ float red[12];

    const int tid = threadIdx.x;
    const int lh = tid & 15, lc = tid >> 4;   // lc 0..47
    const int c  = blockIdx.z;
    const int H0 = blockIdx.x * 12;
    const int o0 = blockIdx.y * DCH;
    const int gh = H0 + lh - 2;
    const bool rowok = ((unsigned)gh < HH);
    const bool lok = (lc > 0), rok = (lc < 47);
    const float mask  = rowok ? 1.f : 0.f;           // gradient row mask
    const float maskl = (rowok && lok) ? 1.f : 0.f;  // halo-site masks
    const float maskr = (rowok && rok) ? 1.f : 0.f;
    const v2f mlv = {maskl, maskl};                  // x-load zero masks
    const v2f mcv = {mask,  mask};
    const v2f mrv = {maskr, maskr};
    const v2f mAv = {maskl, mask};                   // gradient pair masks {gl,g0}
    const v2f mBv = {mask,  maskr};                  // {g1,gr}
    const float em = (lh >= 2 && lh <= 13) ? 1.f : 0.f;

    const int ghc   = min(max(gh, 0), HH - 1);       // row-clamped: always-valid addr
    const int woffc = ghc * WW + (lc << 1);
    const int woffl = lok ? woffc - 2 : woffc;       // w-halo offsets, edge-clamped
    const int woffr = rok ? woffc + 2 : woffc;
    const float* xc = x + (size_t)c * DHW;

    // x window: slices e-1(p), e(m), e+1(n); per slice L/C/R = x[w-2..w+3]
    v2f Lp,Cp,Rp, Lm,Cm,Rm, Ln,Cn,Rn;

    auto loadslice = [&](int e, v2f& L, v2f& C, v2f& R) {
        const int ec = min(max(e, 0), DD - 1);       // depth-clamped
        const float* sp = xc + (size_t)(ec * HW);
        C = *(const v2f*)(sp + woffc);
        L = *(const v2f*)(sp + woffl);
        R = *(const v2f*)(sp + woffr);
        if (e != ec) {                               // uniform branch (edge blocks only)
            L = (v2f){0.f,0.f}; C = (v2f){0.f,0.f}; R = (v2f){0.f,0.f};
        }
        L *= mlv; C *= mcv; R *= mrv;                // 3 pk muls: row/edge zero-pad
    };

    loadslice(o0 - 2, Lp, Cp, Rp);
    loadslice(o0 - 1, Lm, Cm, Rm);

    v2f s2m1[6], s2m2[6];
    #pragma unroll
    for (int f = 0; f < 6; ++f) {
        s2m1[f] = (v2f){0.f,0.f};
        s2m2[f] = (v2f){0.f,0.f};
    }
    v2f hv = {0.f, 0.f};

    #pragma unroll
    for (int k = 0; k < DCH + 2; ++k) {       // 18 slices -> 16 output slices
        const int e = o0 - 1 + k;
        loadslice(e + 1, Ln, Cn, Rn);         // R12-style: load slice e+1, use now

        // depth window (pk)
        const v2f AL = (Lp + Lm) + Ln;
        const v2f AC = (Cp + Cm) + Cn;
        const v2f AR = (Rp + Rm) + Rn;
        const v2f DL = Ln - Lp;
        const v2f DC = Cn - Cp;
        const v2f DR = Rn - Rp;

        // w-convs at sites l,0,1,r
        const v2f SxA = AC - AL;              // {Sxl, Sx0}  pk
        const v2f SxB = AR - AC;              // {Sx1, Sxr}  pk
        const float Txl = fmaf(2.f, AL.y, AL.x + AC.x);
        const float Tx0 = fmaf(2.f, AC.x, AL.y + AC.y);
        const float Tx1 = fmaf(2.f, AC.y, AC.x + AR.x);
        const float Txr = fmaf(2.f, AR.x, AC.y + AR.y);
        const float p01 = DL.y + DC.x, p23 = DC.y + DR.x;
        const float Tdl = DL.x + p01,  Td0 = p01 + DC.y;
        const float Td1 = DC.x + p23,  Tdr = p23 + DR.y;

        // h-convs via DPP; paired-add form -> folds into v_add_f32_dpp
        #define HX(S)  ((dpp_up(S) + (S)) + (dpp_dn(S) + (S)))
        #define HY(T)  (dpp_dn(T) - dpp_up(T))
        #define HZ(T)  ((dpp_up(T) + (T)) + dpp_dn(T))
        v2f gxA = {HX(SxA.x), HX(SxA.y)};  gxA *= mAv;   // {glx, gx0}
        v2f gxB = {HX(SxB.x), HX(SxB.y)};  gxB *= mBv;   // {gx1, grx}
        v2f gyA = {HY(Txl),   HY(Tx0)};    gyA *= mAv;
        v2f gyB = {HY(Tx1),   HY(Txr)};    gyB *= mBv;
        v2f gzA = {HZ(Tdl),   HZ(Td0)};    gzA *= mAv;
        v2f gzB = {HZ(Td1),   HZ(Tdr)};    gzB *= mBv;

        // products: own pair {g0,g1} packed; halo pair {gl,gr} packed
        const v2f gx0v = {gxA.y, gxB.x}, gy0v = {gyA.y, gyB.x}, gz0v = {gzA.y, gzB.x};
        const v2f gxh  = {gxA.x, gxB.y}, gyh  = {gyA.x, gyB.y}, gzh  = {gzA.x, gzB.y};
        const v2f Pxx = gx0v*gx0v, Pyy = gy0v*gy0v, Pzz = gz0v*gz0v;
        const v2f Pxy = gx0v*gy0v, Pxz = gx0v*gz0v, Pyz = gy0v*gz0v;
        const v2f Phxx = gxh*gxh, Phyy = gyh*gyh, Phzz = gzh*gzh;
        const v2f Phxy = gxh*gyh, Phxz = gxh*gzh, Phyz = gyh*gzh;

        // w [1,1,1] on products + h [1,1,1] via fused-DPP adds
        v2f s2c[6];
        #define FIELD(f, Pv, Ph)                                       \
        {   const float s_ = (Pv).x + (Pv).y;                          \
            const v2f Rv = (Ph) + (v2f){s_, s_};                       \
            s2c[f].x = HZ(Rv.x);                                       \
            s2c[f].y = HZ(Rv.y); }
        FIELD(0, Pxx, Phxx)
        FIELD(1, Pyy, Phyy)
        FIELD(2, Pzz, Phzz)
        FIELD(3, Pxy, Phxy)
        FIELD(4, Pxz, Phxz)
        FIELD(5, Pyz, Phyz)
        #undef FIELD
        #undef HX
        #undef HY
        #undef HZ

        if (k >= 2) {   // compile-time under full unroll; emit slice o = e-1
            const v2f sxx = (s2m2[0] + s2m1[0]) + s2c[0];
            const v2f syy = (s2m2[1] + s2m1[1]) + s2c[1];
            const v2f szz = (s2m2[2] + s2m1[2]) + s2c[2];
            const v2f sxy = (s2m2[3] + s2m1[3]) + s2c[3];
            const v2f sxz = (s2m2[4] + s2m1[4]) + s2c[4];
            const v2f syz = (s2m2[5] + s2m1[5]) + s2c[5];
            const v2f det = sxx*(syy*szz - syz*syz)
                          - sxy*(sxy*szz - syz*sxz)
                          + sxz*(sxy*syz - syy*sxz);
            const v2f tr = (sxx + syy) + szz;
            hv += det - KTR*(tr*tr);   // emit-row mask deferred to the end
        }
        #pragma unroll
        for (int f = 0; f < 6; ++f) { s2m2[f] = s2m1[f]; s2m1[f] = s2c[f]; }
        Lp = Lm; Cp = Cm; Rp = Rm;
        Lm = Ln; Cm = Cn; Rm = Rn;
    }

    // non-emitted rows (lh<2 || lh>13) computed finite garbage; zero it here
    float hs = (hv.x + hv.y) * em;
    // block reduce -> per-block partial slot (no atomics, no ws init needed)
    #pragma unroll
    for (int o = 32; o > 0; o >>= 1) hs += __shfl_down(hs, o, 64);
    if ((tid & 63) == 0) red[tid >> 6] = hs;
    __syncthreads();
    if (tid == 0) {
        float s = 0.f;
        #pragma unroll
        for (int i = 0; i < 12; ++i) s += red[i];
        pp[c * 32 + blockIdx.y * 8 + blockIdx.x] = s * INV27C;
    }
}

// One-block selection: sum 32 partials/channel (fixed order -> deterministic),
// parallel rank (== serial strict-> scan with index tiebreak), write sidx[8].
__global__ __launch_bounds__(64)
void topk_select_kernel(const float* __restrict__ pp, int* __restrict__ sidx) {
    __shared__ float pv[CCH];
    const int t = threadIdx.x;
    if (t < CCH) {
        float s = 0.f;
        #pragma unroll
        for (int j = 0; j < 32; ++j) s += pp[t * 32 + j];
        pv[t] = s;
    }
    __syncthreads();
    if (t < CCH) {
        const float v = pv[t];
        int r = 0;
        #pragma unroll
        for (int i = 0; i < CCH; ++i) {
            const float u = pv[i];
            r += (u > v) || (u == v && i < t);
        }
        if (r < 8) sidx[r] = t;
    }
}

// Pure streaming copy: 64 B/thread, selection read once per block.
__global__ __launch_bounds__(256)
void gather_kernel(const float* __restrict__ x, const int* __restrict__ sidx,
                   float4* __restrict__ out) {
    const int j = blockIdx.y;                        // 0..7
    const int cidx = sidx[j];                        // uniform
    const float4* src = (const float4*)(x + (size_t)cidx * DHW);
    float4* dst = out + (size_t)j * CH4;
    const int base = blockIdx.x * 1024 + threadIdx.x;   // 144*1024 == CH4 exact
    #pragma unroll
    for (int t = 0; t < 4; ++t)
        dst[base + t * 256] = src[base + t * 256];
}

extern "C" void kernel_launch(void* const* d_in, const int* in_sizes, int n_in,
                              void* d_out, int out_size, void* d_ws, size_t ws_size,
                              hipStream_t stream) {
    const float* x = (const float*)d_in[0];
    float4* out = reinterpret_cast<float4*>(d_out);
    float* pp = (float*)d_ws;                        // 512 per-block partials (2 KB)
    int* sidx = (int*)(pp + 512);                    // +32 B: selected channels

    dim3 g1(8, NBY, CCH);                            // (8,4,16) = 512 blocks
    harris_sum_kernel<<<g1, NTH, 0, stream>>>(x, pp);

    topk_select_kernel<<<1, 64, 0, stream>>>(pp, sidx);

    dim3 g3(CH4 / 1024, 8, 1);                       // (144, 8)
    gather_kernel<<<g3, 256, 0, stream>>>(x, sidx, out);
}

// Round 4
// 126.129 us; speedup vs baseline: 1.9923x; 1.9923x over previous
//
#include <hip/hip_runtime.h>

#define CCH 16
#define DD 64
#define HH 96
#define WW 96
#define HW (HH*WW)
#define DHW (DD*HH*WW)   // 589824
#define CH4 (DHW/4)      // 147456
#define NTH 768          // 16 lh x 48 lc, 2 w-sites per thread
#define DCH 16           // depth outputs per block
#define NBY (DD/DCH)     // 4 depth chunks
#define KTR 1.08f        // 27 * k_harris (S unscaled by 1/27; ranking-invariant)
#define INV27C (1.f/19683.f)

typedef float v2f __attribute__((ext_vector_type(2)));

// DPP row16 shifts: thread layout is lh-fast (lh = tid & 15), so a DPP row of
// 16 lanes == one h-column; bound_ctrl=true zero-fills at row ends (filled
// sites only feed masked-out outputs). Harris is invariant to an up/down swap.
__device__ __forceinline__ float dpp_up(float v) {
    return __int_as_float(__builtin_amdgcn_update_dpp(
        0, __float_as_int(v), 0x111 /*row_shr:1*/, 0xF, 0xF, true));
}
__device__ __forceinline__ float dpp_dn(float v) {
    return __int_as_float(__builtin_amdgcn_update_dpp(
        0, __float_as_int(v), 0x101 /*row_shl:1*/, 0xF, 0xF, true));
}

// R15 = R14's slim branchless body + two structural fixes:
//  (1) sched_barrier(0x7) at every slice boundary: ALU may cross, VMEM/DS may
//      NOT. R13/R14 spilled (WRITE_SIZE 89/300 MB) because the unconditional
//      loads of the fully-unrolled body were hoisted/clustered en masse by the
//      scheduler (R12's divergent load branches had acted as accidental
//      fences). Pinning VMEM per-slice caps live ranges under the 85-VGPR
//      budget of launch_bounds(768,6).
//  (2) 1-slice prefetch pipeline (f-stage): loads for slice e+2 issue at the
//      top of slice e's body, consumed one full slice later -> s_waitcnt
//      becomes vmcnt(3) with ~a slice of VALU work in between. This attacks
//      the R11/R12 55 us plateau (VALUBusy 54% == load-use stall per slice:
//      ~600 cy compute vs ~500 cy exposed latency).
__global__ __launch_bounds__(NTH, 6)
void harris_sum_kernel(const float* __restrict__ x, float* __restrict__ pp) {
    __shared__ float red[12];

    const int tid = threadIdx.x;
    const int lh = tid & 15, lc = tid >> 4;   // lc 0..47
    const int c  = blockIdx.z;
    const int H0 = blockIdx.x * 12;
    const int o0 = blockIdx.y * DCH;
    const int gh = H0 + lh - 2;
    const bool rowok = ((unsigned)gh < HH);
    const bool lok = (lc > 0), rok = (lc < 47);
    const float mask  = rowok ? 1.f : 0.f;           // gradient row mask
    const float maskl = (rowok && lok) ? 1.f : 0.f;  // halo-site masks
    const float maskr = (rowok && rok) ? 1.f : 0.f;
    const float em = (lh >= 2 && lh <= 13) ? 1.f : 0.f;

    const int ghc   = min(max(gh, 0), HH - 1);       // row-clamped: always-valid addr
    const int woffc = ghc * WW + (lc << 1);
    const int woffl = lok ? woffc - 2 : woffc;       // w-halo offsets, edge-clamped
    const int woffr = rok ? woffc + 2 : woffc;
    const float* xc = x + (size_t)c * DHW;

    // x window: slices e-1(p), e(m), e+1(n), in-flight (f); L/C/R = x[w-2..w+3]
    v2f Lp,Cp,Rp, Lm,Cm,Rm, Ln,Cn,Rn;

    auto loadslice = [&](int e, v2f& L, v2f& C, v2f& R) {
        const int ec = min(max(e, 0), DD - 1);       // depth-clamped (uniform SALU)
        const float* sp = xc + (size_t)(ec * HW);
        C = *(const v2f*)(sp + woffc);
        L = *(const v2f*)(sp + woffl);
        R = *(const v2f*)(sp + woffr);
        if (e != ec) {                               // uniform branch (edge blocks only)
            L = (v2f){0.f,0.f}; C = (v2f){0.f,0.f}; R = (v2f){0.f,0.f};
        }
        // row/edge zero-pad (broadcast-scalar pk muls)
        L *= (v2f){maskl, maskl};
        C *= (v2f){mask,  mask};
        R *= (v2f){maskr, maskr};
    };

    loadslice(o0 - 2, Lp, Cp, Rp);
    loadslice(o0 - 1, Lm, Cm, Rm);
    loadslice(o0,     Ln, Cn, Rn);

    v2f s2m1[6], s2m2[6];
    #pragma unroll
    for (int f = 0; f < 6; ++f) {
        s2m1[f] = (v2f){0.f,0.f};
        s2m2[f] = (v2f){0.f,0.f};
    }
    v2f hv = {0.f, 0.f};

    #pragma unroll
    for (int k = 0; k < DCH + 2; ++k) {       // 18 slices -> 16 output slices
        const int e = o0 - 1 + k;

        // prefetch slice e+2 (consumed next iteration; vmcnt(3) wait pattern)
        v2f Lf = {0.f,0.f}, Cf = {0.f,0.f}, Rf = {0.f,0.f};
        if (k < DCH + 1) loadslice(e + 2, Lf, Cf, Rf);

        // depth window (pk)
        const v2f AL = (Lp + Lm) + Ln;
        const v2f AC = (Cp + Cm) + Cn;
        const v2f AR = (Rp + Rm) + Rn;
        const v2f DL = Ln - Lp;
        const v2f DC = Cn - Cp;
        const v2f DR = Rn - Rp;

        // w-convs at sites l,0,1,r
        const v2f SxA = AC - AL;              // {Sxl, Sx0}  pk
        const v2f SxB = AR - AC;              // {Sx1, Sxr}  pk
        const float Txl = fmaf(2.f, AL.y, AL.x + AC.x);
        const float Tx0 = fmaf(2.f, AC.x, AL.y + AC.y);
        const float Tx1 = fmaf(2.f, AC.y, AC.x + AR.x);
        const float Txr = fmaf(2.f, AR.x, AC.y + AR.y);
        const float p01 = DL.y + DC.x, p23 = DC.y + DR.x;
        const float Tdl = DL.x + p01,  Td0 = p01 + DC.y;
        const float Td1 = DC.x + p23,  Tdr = p23 + DR.y;

        // h-convs via DPP; paired-add form -> folds into v_add_f32_dpp
        #define HX(S)  ((dpp_up(S) + (S)) + (dpp_dn(S) + (S)))
        #define HY(T)  (dpp_dn(T) - dpp_up(T))
        #define HZ(T)  ((dpp_up(T) + (T)) + dpp_dn(T))
        v2f gxA = {HX(SxA.x), HX(SxA.y)};  gxA *= (v2f){maskl, mask};   // {glx, gx0}
        v2f gxB = {HX(SxB.x), HX(SxB.y)};  gxB *= (v2f){mask, maskr};   // {gx1, grx}
        v2f gyA = {HY(Txl),   HY(Tx0)};    gyA *= (v2f){maskl, mask};
        v2f gyB = {HY(Tx1),   HY(Txr)};    gyB *= (v2f){mask, maskr};
        v2f gzA = {HZ(Tdl),   HZ(Td0)};    gzA *= (v2f){maskl, mask};
        v2f gzB = {HZ(Td1),   HZ(Tdr)};    gzB *= (v2f){mask, maskr};

        // products: own pair {g0,g1} packed; halo pair {gl,gr} packed
        const v2f gx0v = {gxA.y, gxB.x}, gy0v = {gyA.y, gyB.x}, gz0v = {gzA.y, gzB.x};
        const v2f gxh  = {gxA.x, gxB.y}, gyh  = {gyA.x, gyB.y}, gzh  = {gzA.x, gzB.y};
        const v2f Pxx = gx0v*gx0v, Pyy = gy0v*gy0v, Pzz = gz0v*gz0v;
        const v2f Pxy = gx0v*gy0v, Pxz = gx0v*gz0v, Pyz = gy0v*gz0v;
        const v2f Phxx = gxh*gxh, Phyy = gyh*gyh, Phzz = gzh*gzh;
        const v2f Phxy = gxh*gyh, Phxz = gxh*gzh, Phyz = gyh*gzh;

        // w [1,1,1] on products + h [1,1,1] via fused-DPP adds
        v2f s2c[6];
        #define FIELD(f, Pv, Ph)                                       \
        {   const float s_ = (Pv).x + (Pv).y;                          \
            const v2f Rv = (Ph) + (v2f){s_, s_};                       \
            s2c[f].x = HZ(Rv.x);                                       \
            s2c[f].y = HZ(Rv.y); }
        FIELD(0, Pxx, Phxx)
        FIELD(1, Pyy, Phyy)
        FIELD(2, Pzz, Phzz)
        FIELD(3, Pxy, Phxy)
        FIELD(4, Pxz, Phxz)
        FIELD(5, Pyz, Phyz)
        #undef FIELD
        #undef HX
        #undef HY
        #undef HZ

        if (k >= 2) {   // compile-time under full unroll; emit slice o = e-1
            const v2f sxx = (s2m2[0] + s2m1[0]) + s2c[0];
            const v2f syy = (s2m2[1] + s2m1[1]) + s2c[1];
            const v2f szz = (s2m2[2] + s2m1[2]) + s2c[2];
            const v2f sxy = (s2m2[3] + s2m1[3]) + s2c[3];
            const v2f sxz = (s2m2[4] + s2m1[4]) + s2c[4];
            const v2f syz = (s2m2[5] + s2m1[5]) + s2c[5];
            const v2f det = sxx*(syy*szz - syz*syz)
                          - sxy*(sxy*szz - syz*sxz)
                          + sxz*(sxy*syz - syy*sxz);
            const v2f tr = (sxx + syy) + szz;
            hv += det - KTR*(tr*tr);   // emit-row mask deferred to the end
        }
        #pragma unroll
        for (int f = 0; f < 6; ++f) { s2m2[f] = s2m1[f]; s2m1[f] = s2c[f]; }
        Lp = Lm; Cp = Cm; Rp = Rm;
        Lm = Ln; Cm = Cn; Rm = Rn;
        Ln = Lf; Cn = Cf; Rn = Rf;

        // fence: ALU(0x1)|VALU(0x2)|SALU(0x4) may cross; VMEM/DS pinned to
        // their slice -> no cross-slice load hoisting (the R13/R14 spill cause)
        __builtin_amdgcn_sched_barrier(0x7);
    }

    // non-emitted rows (lh<2 || lh>13) computed finite garbage; zero it here
    float hs = (hv.x + hv.y) * em;
    // block reduce -> per-block partial slot (no atomics, no ws init needed)
    #pragma unroll
    for (int o = 32; o > 0; o >>= 1) hs += __shfl_down(hs, o, 64);
    if ((tid & 63) == 0) red[tid >> 6] = hs;
    __syncthreads();
    if (tid == 0) {
        float s = 0.f;
        #pragma unroll
        for (int i = 0; i < 12; ++i) s += red[i];
        pp[c * 32 + blockIdx.y * 8 + blockIdx.x] = s * INV27C;
    }
}

// Fused select+gather: every block recomputes the top-8 selection from pp
// (16x32 L2-hit loads + parallel rank -- cheaper than a separate kernel
// launch), then streams its copy tile. Summation order and rank tiebreak are
// identical to the previous split version -> same selection, deterministic.
__global__ __launch_bounds__(256)
void gather_topk_kernel(const float* __restrict__ x, const float* __restrict__ pp,
                        float4* __restrict__ out) {
    __shared__ float pv[CCH];
    __shared__ int sidx[8];
    const int tid = threadIdx.x;
    if (tid < CCH) {
        float s = 0.f;
        #pragma unroll
        for (int j = 0; j < 32; ++j) s += pp[tid * 32 + j];
        pv[tid] = s;   // fixed order -> deterministic across blocks
    }
    __syncthreads();
    if (tid < CCH) {
        const float v = pv[tid];
        int r = 0;
        #pragma unroll
        for (int i = 0; i < CCH; ++i) {
            const float u = pv[i];
            r += (u > v) || (u == v && i < tid);
        }
        if (r < 8) sidx[r] = tid;
    }
    __syncthreads();
    const int j = blockIdx.y;                        // 0..7
    const int cidx = sidx[j];                        // uniform
    const float4* src = (const float4*)(x + (size_t)cidx * DHW);
    float4* dst = out + (size_t)j * CH4;
    const int base = blockIdx.x * 1024 + tid;        // 144*1024 == CH4 exact
    #pragma unroll
    for (int t = 0; t < 4; ++t)
        dst[base + t * 256] = src[base + t * 256];
}

extern "C" void kernel_launch(void* const* d_in, const int* in_sizes, int n_in,
                              void* d_out, int out_size, void* d_ws, size_t ws_size,
                              hipStream_t stream) {
    const float* x = (const float*)d_in[0];
    float4* out = reinterpret_cast<float4*>(d_out);
    float* pp = (float*)d_ws;                        // 512 per-block partials (2 KB)

    dim3 g1(8, NBY, CCH);                            // (8,4,16) = 512 blocks
    harris_sum_kernel<<<g1, NTH, 0, stream>>>(x, pp);

    dim3 g2(CH4 / 1024, 8, 1);                       // (144, 8)
    gather_topk_kernel<<<g2, 256, 0, stream>>>(x, pp, out);
}